// Round 1
// baseline (193.147 us; speedup 1.0000x reference)
//
#include <hip/hip_runtime.h>
#include <stdint.h>

// Bitnet int8 x int2 GEMM: C[M,N](i32) = A[M,K](i8) . W[N,K]^T, W unpacked from
// 2-bit interleaved storage B[N,K/4].
// Harness passes integer inputs as int32 -> prepass packs low bytes into d_ws.

#define MM 1024
#define NN 11008
#define KK 4096

using i32x4  = __attribute__((ext_vector_type(4))) int;
using i32x16 = __attribute__((ext_vector_type(16))) int;

// Pack low byte of each int32 into a byte stream. Each thread handles 16 elems.
__global__ __launch_bounds__(256) void pack_low8(const int* __restrict__ src,
                                                 uint8_t* __restrict__ dst,
                                                 int n16) {
    int idx = blockIdx.x * 256 + threadIdx.x;
    if (idx >= n16) return;
    const i32x4* s4 = (const i32x4*)src;
    i32x4 o;
#pragma unroll
    for (int q = 0; q < 4; ++q) {
        i32x4 v = s4[(size_t)idx * 4 + q];
        o[q] = (v[0] & 0xFF) | ((v[1] & 0xFF) << 8) | ((v[2] & 0xFF) << 16)
               | ((int)((uint32_t)(v[3] & 0xFF) << 24));
    }
    *(i32x4*)(dst + (size_t)idx * 16) = o;
}

// GEMM: block = 128x128 output tile, 4 waves (2x2), wave = 64x64 via 2x2
// mfma_i32_32x32x32_i8. K-loop step 32. Fragments loaded directly from global
// (packed A/B are small: 4 MB + 11 MB, L2/L3-resident).
__global__ __launch_bounds__(256) void bitnet_gemm(const uint8_t* __restrict__ Ap,
                                                   const uint8_t* __restrict__ Bp,
                                                   int* __restrict__ C) {
    const int lane  = threadIdx.x & 63;
    const int wave  = threadIdx.x >> 6;      // 0..3
    const int wr    = wave >> 1;             // wave row (0..1)
    const int wc    = wave & 1;              // wave col (0..1)
    const int l31   = lane & 31;
    const int khalf = lane >> 5;             // 0 or 1

    const int brow = blockIdx.y * 128;
    const int bcol = blockIdx.x * 128;

    // A fragment rows for this wave's two 32-row tiles
    const int arow0 = brow + wr * 64 + l31;
    const int bn0   = bcol + wc * 64 + l31;

    // A: lane holds A[row][k0 + khalf*16 + e], e=0..15 (16 contiguous bytes)
    const uint8_t* pa0 = Ap + (size_t)arow0 * KK + khalf * 16;
    const uint8_t* pa1 = pa0 + (size_t)32 * KK;
    // B packed: 16 weights = 4 bytes at byte offset n*(K/4) + k/4
    const uint8_t* pb0 = Bp + (size_t)bn0 * (KK / 4) + khalf * 4;
    const uint8_t* pb1 = pb0 + (size_t)32 * (KK / 4);

    i32x16 acc[2][2] = {};

#pragma unroll 4
    for (int k0 = 0; k0 < KK; k0 += 32) {
        i32x4 a0 = *(const i32x4*)(pa0 + k0);
        i32x4 a1 = *(const i32x4*)(pa1 + k0);
        uint32_t p0 = *(const uint32_t*)(pb0 + (k0 >> 2));
        uint32_t p1 = *(const uint32_t*)(pb1 + (k0 >> 2));

        // decode: element e=4i+j of the 16-group = (byte_j >> 2i) & 3
        // reg i, byte j of the MFMA fragment = element 4i+j  -> direct match
        i32x4 b0, b1;
#pragma unroll
        for (int i = 0; i < 4; ++i) {
            b0[i] = (int)((p0 >> (2 * i)) & 0x03030303u);
            b1[i] = (int)((p1 >> (2 * i)) & 0x03030303u);
        }

        acc[0][0] = __builtin_amdgcn_mfma_i32_32x32x32_i8(a0, b0, acc[0][0], 0, 0, 0);
        acc[0][1] = __builtin_amdgcn_mfma_i32_32x32x32_i8(a0, b1, acc[0][1], 0, 0, 0);
        acc[1][0] = __builtin_amdgcn_mfma_i32_32x32x32_i8(a1, b0, acc[1][0], 0, 0, 0);
        acc[1][1] = __builtin_amdgcn_mfma_i32_32x32x32_i8(a1, b1, acc[1][1], 0, 0, 0);
    }

    // C/D layout (HW-verified, dtype-independent): col = lane&31,
    // row = (r&3) + 8*(r>>2) + 4*(lane>>5)
#pragma unroll
    for (int mi = 0; mi < 2; ++mi) {
#pragma unroll
        for (int ni = 0; ni < 2; ++ni) {
            const int colg = bcol + wc * 64 + ni * 32 + l31;
#pragma unroll
            for (int r = 0; r < 16; ++r) {
                const int rowin = (r & 3) + 8 * (r >> 2) + 4 * khalf;
                const int rowg  = brow + wr * 64 + mi * 32 + rowin;
                C[(size_t)rowg * NN + colg] = acc[mi][ni][r];
            }
        }
    }
}

extern "C" void kernel_launch(void* const* d_in, const int* in_sizes, int n_in,
                              void* d_out, int out_size, void* d_ws, size_t ws_size,
                              hipStream_t stream) {
    const int* A32 = (const int*)d_in[0];   // [M,K] int8 values in int32
    const int* B32 = (const int*)d_in[1];   // [N,K/4] packed bytes in int32
    int* C = (int*)d_out;                   // [M,N] int32

    uint8_t* Apack = (uint8_t*)d_ws;                    // M*K bytes = 4 MiB
    uint8_t* Bpack = Apack + (size_t)MM * KK;           // N*K/4 bytes = 10.75 MiB

    const int an16 = MM * KK / 16;          // 262144
    const int bn16 = NN * (KK / 4) / 16;    // 704512

    pack_low8<<<dim3((an16 + 255) / 256), dim3(256), 0, stream>>>(A32, Apack, an16);
    pack_low8<<<dim3((bn16 + 255) / 256), dim3(256), 0, stream>>>(B32, Bpack, bn16);

    bitnet_gemm<<<dim3(NN / 128, MM / 128), dim3(256), 0, stream>>>(Apack, Bpack, C);
}

// Round 2
// 72.549 us; speedup vs baseline: 2.6623x; 2.6623x over previous
//
#include <hip/hip_runtime.h>
#include <stdint.h>

// Bitnet int8 x int2 GEMM: C[M,N](i32) = A[M,K](i8) . W[N,K]^T
// Round 2: prepass re-layout into tile-contiguous pre-swizzled form +
// global_load_lds double-buffered 2-phase pipeline.

#define MM 1024
#define NN 11008
#define KK 4096
#define KSTEPS (KK / 64)   // 64 K-steps of 64

using i32x4  = __attribute__((ext_vector_type(4))) int;
using i32x16 = __attribute__((ext_vector_type(16))) int;

__device__ __forceinline__ int pack4(i32x4 v) {
    return (int)(((uint32_t)v[0] & 0xFFu) | (((uint32_t)v[1] & 0xFFu) << 8)
               | (((uint32_t)v[2] & 0xFFu) << 16) | (((uint32_t)v[3] & 0xFFu) << 24));
}

// A prepass: A32[M][K] int32 -> A2[kstep][m][64] bytes, 16B chunks XOR-swizzled
// by (m&3) so GEMM ds_read_b128 is bank-optimal. Thread t: m = t>>8, k16 = t&255.
__global__ __launch_bounds__(256) void prep_A(const int* __restrict__ src,
                                              uint8_t* __restrict__ dst) {
    const int t = blockIdx.x * 256 + threadIdx.x;   // < M*K/16 = 262144
    const int m = t >> 8, k16 = t & 255;
    const i32x4* s4 = (const i32x4*)(src + (((size_t)m << 8) + k16) * 16);
    i32x4 o;
#pragma unroll
    for (int q = 0; q < 4; ++q) o[q] = pack4(s4[q]);
    const int kstep = k16 >> 2;
    const int chunk = (k16 & 3) ^ (m & 3);
    *(i32x4*)(dst + (size_t)kstep * (MM * 64) + m * 64 + chunk * 16) = o;
}

// B prepass: B32[N][K/4] int32 -> B2[kstep][n][16] bytes (packed 2-bit kept
// packed), dword slot d -> d ^ ((n>>3)&1) on bit0 (2-way residual = free).
__global__ __launch_bounds__(256) void prep_B(const int* __restrict__ src,
                                              uint8_t* __restrict__ dst) {
    const int t = blockIdx.x * 256 + threadIdx.x;   // < N*64 = 704512
    const int n = t >> 6, kg = t & 63;              // kg == kstep
    const i32x4* s4 = (const i32x4*)(src + (((size_t)n << 6) + kg) * 16);
    int w[4];
#pragma unroll
    for (int d = 0; d < 4; ++d) w[d] = pack4(s4[d]);
    const int x = (n >> 3) & 1;
    i32x4 o;
    o[0] = x ? w[1] : w[0];
    o[1] = x ? w[0] : w[1];
    o[2] = x ? w[3] : w[2];
    o[3] = x ? w[2] : w[3];
    *(i32x4*)(dst + (size_t)kg * (NN * 16) + n * 16) = o;
}

#define GLOAD_LDS16(g, l) __builtin_amdgcn_global_load_lds(                    \
        (const __attribute__((address_space(1))) uint32_t*)(g),                \
        (__attribute__((address_space(3))) uint32_t*)(l), 16, 0, 0)

// GEMM: 128x128 block tile, 4 waves 2x2, wave = 64x64 via 2x2x2
// mfma_i32_32x32x32_i8 per K-step of 64. Double-buffered LDS staging.
__global__ __launch_bounds__(256) void bitnet_gemm(const uint8_t* __restrict__ A2,
                                                   const uint8_t* __restrict__ B2,
                                                   int* __restrict__ C) {
    const int t    = threadIdx.x;
    const int lane = t & 63, wave = t >> 6;
    const int wr   = wave >> 1, wc = wave & 1;
    const int l31  = lane & 31, h = lane >> 5;
    const int brow = blockIdx.y * 128, bcol = blockIdx.x * 128;

    __shared__ __align__(16) uint8_t As[2][8192];   // [buf][m_local*64 + chunk'*16 + b]
    __shared__ __align__(16) uint8_t Bs[2][2048];   // [buf][n_local*16 + d'*4 + b]

    // LDS read byte offsets (all-static after unroll)
    int a_off[2][2], b_off[2][2];
#pragma unroll
    for (int mi = 0; mi < 2; ++mi)
#pragma unroll
        for (int kk2 = 0; kk2 < 2; ++kk2) {
            const int row   = wr * 64 + mi * 32 + l31;
            const int chunk = (kk2 * 2 + h) ^ (row & 3);
            a_off[mi][kk2]  = row * 64 + chunk * 16;
        }
#pragma unroll
    for (int ni = 0; ni < 2; ++ni)
#pragma unroll
        for (int kk2 = 0; kk2 < 2; ++kk2) {
            const int n   = wc * 64 + ni * 32 + l31;
            const int d   = kk2 * 2 + (h ^ ((n >> 3) & 1));
            b_off[ni][kk2] = n * 16 + d * 4;
        }

    const uint8_t* gA = A2 + (size_t)brow * 64 + t * 16;   // tile-contiguous
    const uint8_t* gB = B2 + (size_t)bcol * 16 + t * 16;   // valid for t<128

    i32x16 acc[2][2] = {};

    auto STAGE = [&](int buf, int ks) {
        const uint8_t* at = gA + (size_t)ks * (MM * 64);
        GLOAD_LDS16(at,        &As[buf][wave * 1024]);
        GLOAD_LDS16(at + 4096, &As[buf][4096 + wave * 1024]);
        if (wave < 2) {
            const uint8_t* bt = gB + (size_t)ks * (NN * 16);
            GLOAD_LDS16(bt, &Bs[buf][wave * 1024]);
        }
    };

    auto COMPUTE = [&](int buf) {
        const uint8_t* ab = As[buf];
        const uint8_t* bb = Bs[buf];
#pragma unroll
        for (int kk2 = 0; kk2 < 2; ++kk2) {
            i32x4 a0 = *(const i32x4*)(ab + a_off[0][kk2]);
            i32x4 a1 = *(const i32x4*)(ab + a_off[1][kk2]);
            const uint32_t p0 = *(const uint32_t*)(bb + b_off[0][kk2]);
            const uint32_t p1 = *(const uint32_t*)(bb + b_off[1][kk2]);
            i32x4 b0, b1;
#pragma unroll
            for (int i = 0; i < 4; ++i) {
                b0[i] = (int)((p0 >> (2 * i)) & 0x03030303u);
                b1[i] = (int)((p1 >> (2 * i)) & 0x03030303u);
            }
            acc[0][0] = __builtin_amdgcn_mfma_i32_32x32x32_i8(a0, b0, acc[0][0], 0, 0, 0);
            acc[0][1] = __builtin_amdgcn_mfma_i32_32x32x32_i8(a0, b1, acc[0][1], 0, 0, 0);
            acc[1][0] = __builtin_amdgcn_mfma_i32_32x32x32_i8(a1, b0, acc[1][0], 0, 0, 0);
            acc[1][1] = __builtin_amdgcn_mfma_i32_32x32x32_i8(a1, b1, acc[1][1], 0, 0, 0);
        }
    };

    STAGE(0, 0);
    __syncthreads();

#pragma unroll 1
    for (int ks = 0; ks < KSTEPS - 2; ks += 2) {
        STAGE(1, ks + 1);
        COMPUTE(0);
        __syncthreads();
        STAGE(0, ks + 2);
        COMPUTE(1);
        __syncthreads();
    }
    STAGE(1, KSTEPS - 1);
    COMPUTE(0);
    __syncthreads();
    COMPUTE(1);

    // C write: col = lane&31, row = (r&3) + 8*(r>>2) + 4*(lane>>5)
#pragma unroll
    for (int mi = 0; mi < 2; ++mi)
#pragma unroll
        for (int ni = 0; ni < 2; ++ni) {
            const int colg = bcol + wc * 64 + ni * 32 + l31;
#pragma unroll
            for (int r = 0; r < 16; ++r) {
                const int rowin = (r & 3) + 8 * (r >> 2) + 4 * h;
                const int rowg  = brow + wr * 64 + mi * 32 + rowin;
                C[(size_t)rowg * NN + colg] = acc[mi][ni][r];
            }
        }
}

extern "C" void kernel_launch(void* const* d_in, const int* in_sizes, int n_in,
                              void* d_out, int out_size, void* d_ws, size_t ws_size,
                              hipStream_t stream) {
    const int* A32 = (const int*)d_in[0];   // [M,K] int8 values in int32
    const int* B32 = (const int*)d_in[1];   // [N,K/4] packed bytes in int32
    int* C = (int*)d_out;                   // [M,N] int32

    uint8_t* A2 = (uint8_t*)d_ws;                      // 4 MiB
    uint8_t* B2 = A2 + (size_t)MM * KK;                // 10.75 MiB

    prep_A<<<dim3((MM * KK / 16) / 256), dim3(256), 0, stream>>>(A32, A2);
    prep_B<<<dim3((NN * 64) / 256), dim3(256), 0, stream>>>(B32, B2);
    bitnet_gemm<<<dim3(NN / 128, MM / 128), dim3(256), 0, stream>>>(A2, B2, C);
}